// Round 1
// baseline (351.397 us; speedup 1.0000x reference)
//
#include <hip/hip_runtime.h>
#include <stdint.h>

// Problem constants
#define BB    64
#define CC    100
#define NBPER 150
#define NBOX  9600
#define FEAT  2052
#define KP    2112      // FEAT padded to 33*64 for BK=64 MFMA loop
#define NOUT  2048
#define MR    6400      // BB*CC rows of x / support

typedef __attribute__((ext_vector_type(8))) short   short8;
typedef __attribute__((ext_vector_type(4))) float   floatx4;

__device__ __forceinline__ unsigned short f2bf(float f) {
  unsigned int u = __float_as_uint(f);
  u += 0x7FFFu + ((u >> 16) & 1u);   // RNE
  return (unsigned short)(u >> 16);
}

// async global->LDS, 16B per lane. LDS dest must be wave-uniform base; HW does base + lane*16.
__device__ __forceinline__ void async16(const void* g, void* l) {
  __builtin_amdgcn_global_load_lds((__attribute__((address_space(1))) void*)(g),
                                   (__attribute__((address_space(3))) void*)(l),
                                   16, 0, 0);
}

// ---------------------------------------------------------------------------
// K0: gc_w [2052][2048] fp32  ->  gcwT [2048][2112] bf16 (K-major, zero-padded)
// ---------------------------------------------------------------------------
__global__ __launch_bounds__(256) void k_transpose(const float* __restrict__ gcw,
                                                   unsigned short* __restrict__ gcwT) {
  __shared__ float tile[32][33];
  const int ko = blockIdx.x;  // 0..65
  const int oo = blockIdx.y;  // 0..63
  const int tx = threadIdx.x, ty = threadIdx.y;
#pragma unroll
  for (int i = 0; i < 4; ++i) {
    const int k = ko * 32 + ty + i * 8;
    const int o = oo * 32 + tx;
    tile[ty + i * 8][tx] = (k < FEAT) ? gcw[(size_t)k * NOUT + o] : 0.f;
  }
  __syncthreads();
#pragma unroll
  for (int i = 0; i < 4; ++i) {
    const int o = oo * 32 + ty + i * 8;
    const int k = ko * 32 + tx;
    gcwT[(size_t)o * KP + k] = f2bf(tile[tx][ty + i * 8]);
  }
}

// ---------------------------------------------------------------------------
// KA: per (image, category) bucket, record up to 3 box indices in stable order
// ---------------------------------------------------------------------------
__global__ __launch_bounds__(256) void k_bucket(const int* __restrict__ labels,
                                                int* __restrict__ boxidx) {
  __shared__ int lab[NBPER];
  const int b = blockIdx.x, tid = threadIdx.x;
  if (tid < NBPER) lab[tid] = labels[b * NBPER + tid];
  __syncthreads();
  if (tid < CC) {
    int cnt = 0;
    int out[3] = {-1, -1, -1};
    for (int i = 0; i < NBPER; ++i) {
      if (lab[i] == tid + 1 && cnt < 3) { out[cnt] = b * NBPER + i; ++cnt; }
    }
    const int base = (b * CC + tid) * 3;
    boxidx[base] = out[0]; boxidx[base + 1] = out[1]; boxidx[base + 2] = out[2];
  }
}

// ---------------------------------------------------------------------------
// KB: x[b,c,d] = lin_b + sum_slot lin_w[slot]*full[box][d], bf16, K-padded
// ---------------------------------------------------------------------------
__global__ __launch_bounds__(256) void k_buildx(const float* __restrict__ imgf,
                                                const float* __restrict__ bbox,
                                                const float* __restrict__ lw,
                                                const float* __restrict__ lb,
                                                const int* __restrict__ boxidx,
                                                unsigned short* __restrict__ xbf) {
  const int c = blockIdx.x, b = blockIdx.y;
  const int r = b * CC + c;
  const int base = r * 3;
  const int i0 = boxidx[base], i1 = boxidx[base + 1], i2 = boxidx[base + 2];
  const float w0 = lw[0], w1 = lw[1], w2 = lw[2], bias = lb[0];
  for (int s = threadIdx.x; s < KP / 8; s += 256) {
    const int d0 = s * 8;
    float v[8];
#pragma unroll
    for (int q = 0; q < 8; ++q) v[q] = 0.f;
    if (d0 < 2048) {
      if (i0 >= 0) {
        const float4* p = (const float4*)(imgf + (size_t)i0 * 2048 + d0);
        float4 u0 = p[0], u1 = p[1];
        v[0] += w0 * u0.x; v[1] += w0 * u0.y; v[2] += w0 * u0.z; v[3] += w0 * u0.w;
        v[4] += w0 * u1.x; v[5] += w0 * u1.y; v[6] += w0 * u1.z; v[7] += w0 * u1.w;
      }
      if (i1 >= 0) {
        const float4* p = (const float4*)(imgf + (size_t)i1 * 2048 + d0);
        float4 u0 = p[0], u1 = p[1];
        v[0] += w1 * u0.x; v[1] += w1 * u0.y; v[2] += w1 * u0.z; v[3] += w1 * u0.w;
        v[4] += w1 * u1.x; v[5] += w1 * u1.y; v[6] += w1 * u1.z; v[7] += w1 * u1.w;
      }
      if (i2 >= 0) {
        const float4* p = (const float4*)(imgf + (size_t)i2 * 2048 + d0);
        float4 u0 = p[0], u1 = p[1];
        v[0] += w2 * u0.x; v[1] += w2 * u0.y; v[2] += w2 * u0.z; v[3] += w2 * u0.w;
        v[4] += w2 * u1.x; v[5] += w2 * u1.y; v[6] += w2 * u1.z; v[7] += w2 * u1.w;
      }
#pragma unroll
      for (int q = 0; q < 8; ++q) v[q] += bias;
    } else if (d0 == 2048) {
      // cols 2048..2051 = bbox, 2052..2055 = pad(0)
      if (i0 >= 0) { float4 u = *(const float4*)(bbox + (size_t)i0 * 4);
        v[0] += w0 * u.x; v[1] += w0 * u.y; v[2] += w0 * u.z; v[3] += w0 * u.w; }
      if (i1 >= 0) { float4 u = *(const float4*)(bbox + (size_t)i1 * 4);
        v[0] += w1 * u.x; v[1] += w1 * u.y; v[2] += w1 * u.z; v[3] += w1 * u.w; }
      if (i2 >= 0) { float4 u = *(const float4*)(bbox + (size_t)i2 * 4);
        v[0] += w2 * u.x; v[1] += w2 * u.y; v[2] += w2 * u.z; v[3] += w2 * u.w; }
      v[0] += bias; v[1] += bias; v[2] += bias; v[3] += bias;
    } // d0 > 2048: zero padding
    unsigned short o[8] __attribute__((aligned(16)));
#pragma unroll
    for (int q = 0; q < 8; ++q) o[q] = f2bf(v[q]);
    *(uint4*)(xbf + (size_t)r * KP + d0) = *(const uint4*)o;
  }
}

// ---------------------------------------------------------------------------
// KC: support[6400][2048] fp32 = x_bf16[6400][2112] @ gcwT[2048][2112]^T
// 128x128 tile, BK=64, bf16 MFMA 16x16x32, global_load_lds width-16 staging,
// k-rotation swizzle (element (m,k) stored at m*64 + ((k + 8*(m&7)) & 63)).
// ---------------------------------------------------------------------------
__global__ __launch_bounds__(256) void k_gemm1(const unsigned short* __restrict__ A,
                                               const unsigned short* __restrict__ Bt,
                                               float* __restrict__ Cm) {
  __shared__ unsigned short Asm[128 * 64] __attribute__((aligned(16)));
  __shared__ unsigned short Bsm[128 * 64] __attribute__((aligned(16)));
  const int tid  = threadIdx.x;
  const int lane = tid & 63;
  const int w    = tid >> 6;          // wave 0..3
  const int m0   = blockIdx.y * 128;  // 50 tiles
  const int n0   = blockIdx.x * 128;  // 16 tiles
  const int wm   = (w & 1) * 64;
  const int wn   = (w >> 1) * 64;
  // staging: lane l fills LDS chunk elements [l*8, l*8+8) = row chunk*8+(l>>3), perm-slots (l&7)*8..
  const int srow = lane >> 3;                      // row within 8-row chunk (== m&7)
  const int gk   = (((lane & 7) - srow) & 7) * 8;  // global k start for this lane (swizzle inverse)
  const int quad = lane >> 4;
  const int lrow = lane & 15;
  const int rot  = (lane & 7) * 8;                 // == 8*(m&7) for fragment rows

  floatx4 acc[4][4] = {};

  for (int kb = 0; kb < KP / 64; ++kb) {
    const int k0 = kb * 64;
#pragma unroll
    for (int t = 0; t < 4; ++t) {
      const int chunk = t * 4 + w;
      const int row = chunk * 8 + srow;
      async16(A  + (size_t)(m0 + row) * KP + (k0 + gk), &Asm[chunk * 512]);
      async16(Bt + (size_t)(n0 + row) * KP + (k0 + gk), &Bsm[chunk * 512]);
    }
    __syncthreads();  // drains vmcnt (global_load_lds) + barrier
#pragma unroll
    for (int kp = 0; kp < 2; ++kp) {
      const int koff = (kp * 32 + quad * 8 + rot) & 63;
      short8 af[4], bfr[4];
#pragma unroll
      for (int i = 0; i < 4; ++i)
        af[i]  = *(const short8*)&Asm[(wm + i * 16 + lrow) * 64 + koff];
#pragma unroll
      for (int j = 0; j < 4; ++j)
        bfr[j] = *(const short8*)&Bsm[(wn + j * 16 + lrow) * 64 + koff];
#pragma unroll
      for (int i = 0; i < 4; ++i)
#pragma unroll
        for (int j = 0; j < 4; ++j)
          acc[i][j] = __builtin_amdgcn_mfma_f32_16x16x32_bf16(af[i], bfr[j], acc[i][j], 0, 0, 0);
    }
    __syncthreads();
  }
  // epilogue: C/D layout col=lane&15, row=(lane>>4)*4+reg
#pragma unroll
  for (int i = 0; i < 4; ++i)
#pragma unroll
    for (int j = 0; j < 4; ++j) {
      const int col = n0 + wn + j * 16 + lrow;
#pragma unroll
      for (int rr = 0; rr < 4; ++rr) {
        const int row = m0 + wm + i * 16 + quad * 4 + rr;
        Cm[(size_t)row * NOUT + col] = acc[i][j][rr];
      }
    }
}

// ---------------------------------------------------------------------------
// KD: out[b,o] = sum_c g[b,c] * lrelu( sum_n (X[c,n]+adj[b,c,n]) * S[b,n,o] + gc_b[o] )
// fp32, n chunked by 32 through LDS, per-thread 4c x 16o register tile.
// ---------------------------------------------------------------------------
__global__ __launch_bounds__(256) void k_gemm2(const float* __restrict__ X,
                                               const float* __restrict__ adj,
                                               const float* __restrict__ S,
                                               const float* __restrict__ gf,
                                               const float* __restrict__ gcb,
                                               float* __restrict__ outp) {
  __shared__ float A2T[32 * 132] __attribute__((aligned(16)));  // [nl][c padded 128, stride 132]
  __shared__ float Ssm[32 * 128] __attribute__((aligned(16)));  // [nl][o]
  __shared__ float red[32 * 128] __attribute__((aligned(16)));
  __shared__ float red2[256];
  const int tid = threadIdx.x;
  const int o0  = blockIdx.x * 128;
  const int b   = blockIdx.y;
  const int tc  = tid & 31;   // c-chunk: c = tc*4..tc*4+3
  const int to  = tid >> 5;   // o-chunk: o = to*16..to*16+15

  float acc[4][16];
#pragma unroll
  for (int cl = 0; cl < 4; ++cl)
#pragma unroll
    for (int j = 0; j < 16; ++j) acc[cl][j] = 0.f;

  for (int nb = 0; nb < 4; ++nb) {
    __syncthreads();
    // stage A2T chunk (coalesced over n), transposed into LDS
    for (int idx = tid; idx < CC * 32; idx += 256) {
      const int c = idx >> 5, nl = idx & 31;
      const int n = nb * 32 + nl;
      float v = 0.f;
      if (n < CC) v = X[c * CC + n] + adj[b * (CC * CC) + c * CC + n];
      A2T[nl * 132 + c] = v;
    }
    for (int idx = tid; idx < 28 * 32; idx += 256) {
      const int c = CC + (idx >> 5), nl = idx & 31;
      A2T[nl * 132 + c] = 0.f;
    }
    // stage S chunk (coalesced over o)
    for (int idx = tid; idx < 32 * 128; idx += 256) {
      const int nl = idx >> 7, ol = idx & 127;
      const int n = nb * 32 + nl;
      Ssm[nl * 128 + ol] = (n < CC) ? S[(size_t)(b * CC + n) * NOUT + o0 + ol] : 0.f;
    }
    __syncthreads();
    const int nlim = (nb == 3) ? 4 : 32;  // n=100 total
    for (int nl = 0; nl < nlim; ++nl) {
      float a[4] __attribute__((aligned(16)));
      float s[16] __attribute__((aligned(16)));
      *(float4*)a = *(const float4*)&A2T[nl * 132 + tc * 4];
#pragma unroll
      for (int q = 0; q < 4; ++q)
        *(float4*)(s + q * 4) = *(const float4*)&Ssm[nl * 128 + to * 16 + q * 4];
#pragma unroll
      for (int cl = 0; cl < 4; ++cl)
#pragma unroll
        for (int j = 0; j < 16; ++j) acc[cl][j] += a[cl] * s[j];
    }
  }
  // epilogue: bias + leaky_relu + attention weight, then cross-tc reduction
  float gcbv[16];
#pragma unroll
  for (int j = 0; j < 16; ++j) gcbv[j] = gcb[o0 + to * 16 + j];
  float part[16];
#pragma unroll
  for (int j = 0; j < 16; ++j) part[j] = 0.f;
#pragma unroll
  for (int cl = 0; cl < 4; ++cl) {
    const int c = tc * 4 + cl;
    if (c < CC) {
      const float gw = gf[b * CC + c];
#pragma unroll
      for (int j = 0; j < 16; ++j) {
        float t = acc[cl][j] + gcbv[j];
        t = (t > 0.f) ? t : 0.01f * t;
        part[j] += gw * t;
      }
    }
  }
#pragma unroll
  for (int j = 0; j < 16; ++j) red[tc * 128 + to * 16 + j] = part[j];
  __syncthreads();
  {
    const int o = tid & 127, h = tid >> 7;
    float sum = 0.f;
#pragma unroll
    for (int t = 0; t < 16; ++t) sum += red[(h * 16 + t) * 128 + o];
    red2[tid] = sum;
  }
  __syncthreads();
  if (tid < 128) outp[(size_t)b * NOUT + o0 + tid] = red2[tid] + red2[128 + tid];
}

// ---------------------------------------------------------------------------
extern "C" void kernel_launch(void* const* d_in, const int* in_sizes, int n_in,
                              void* d_out, int out_size, void* d_ws, size_t ws_size,
                              hipStream_t stream) {
  const float* imgf   = (const float*)d_in[0];
  const float* bbox   = (const float*)d_in[1];
  const float* gfeat  = (const float*)d_in[2];
  const float* adj    = (const float*)d_in[3];
  const float* X      = (const float*)d_in[4];
  const float* lw     = (const float*)d_in[5];
  const float* lb     = (const float*)d_in[6];
  const float* gcw    = (const float*)d_in[7];
  const float* gcb    = (const float*)d_in[8];
  const int*   labels = (const int*)d_in[9];
  // d_in[10] (batch) is implied by layout: box i belongs to image i/150.

  char* ws = (char*)d_ws;
  // ws layout (all offsets 16B-aligned): total ~88.2 MB
  int*            boxidx  = (int*)(ws);                                    //    76,800 B
  unsigned short* xbf     = (unsigned short*)(ws + 76800);                 // 27,033,600 B
  unsigned short* gcwT    = (unsigned short*)(ws + 76800 + 27033600);      //  8,650,752 B
  float*          support = (float*)(ws + 76800 + 27033600 + 8650752);     // 52,428,800 B
  float*          outp    = (float*)d_out;

  k_transpose<<<dim3(KP / 32, NOUT / 32), dim3(32, 8), 0, stream>>>(gcw, gcwT);
  k_bucket<<<dim3(BB), dim3(256), 0, stream>>>(labels, boxidx);
  k_buildx<<<dim3(CC, BB), dim3(256), 0, stream>>>(imgf, bbox, lw, lb, boxidx, xbf);
  k_gemm1<<<dim3(NOUT / 128, MR / 128), dim3(256), 0, stream>>>(xbf, gcwT, support);
  k_gemm2<<<dim3(NOUT / 128, BB), dim3(256), 0, stream>>>(X, adj, support, gfeat, gcb, outp);
}

// Round 2
// 296.416 us; speedup vs baseline: 1.1855x; 1.1855x over previous
//
#include <hip/hip_runtime.h>
#include <stdint.h>

// Problem constants
#define BB    64
#define CC    100
#define NBPER 150
#define NBOX  9600
#define FEAT  2052
#define KP    2112      // FEAT padded to 33*64 for BK=64 MFMA loop
#define NOUT  2048
#define MR    6400      // BB*CC rows of x / support

typedef __attribute__((ext_vector_type(8))) short   short8;
typedef __attribute__((ext_vector_type(4))) float   floatx4;

__device__ __forceinline__ unsigned short f2bf(float f) {
  unsigned int u = __float_as_uint(f);
  u += 0x7FFFu + ((u >> 16) & 1u);   // RNE
  return (unsigned short)(u >> 16);
}

// async global->LDS, 16B per lane. LDS dest must be wave-uniform base; HW does base + lane*16.
__device__ __forceinline__ void async16(const void* g, void* l) {
  __builtin_amdgcn_global_load_lds((__attribute__((address_space(1))) void*)(g),
                                   (__attribute__((address_space(3))) void*)(l),
                                   16, 0, 0);
}

// ---------------------------------------------------------------------------
// K0: gc_w [2052][2048] fp32  ->  gcwT [2048][2112] bf16 (K-major, zero-padded)
// ---------------------------------------------------------------------------
__global__ __launch_bounds__(256) void k_transpose(const float* __restrict__ gcw,
                                                   unsigned short* __restrict__ gcwT) {
  __shared__ float tile[32][33];
  const int ko = blockIdx.x;  // 0..65
  const int oo = blockIdx.y;  // 0..63
  const int tx = threadIdx.x, ty = threadIdx.y;
#pragma unroll
  for (int i = 0; i < 4; ++i) {
    const int k = ko * 32 + ty + i * 8;
    const int o = oo * 32 + tx;
    tile[ty + i * 8][tx] = (k < FEAT) ? gcw[(size_t)k * NOUT + o] : 0.f;
  }
  __syncthreads();
#pragma unroll
  for (int i = 0; i < 4; ++i) {
    const int o = oo * 32 + ty + i * 8;
    const int k = ko * 32 + tx;
    gcwT[(size_t)o * KP + k] = f2bf(tile[tx][ty + i * 8]);
  }
}

// ---------------------------------------------------------------------------
// KA: per (image, category) bucket, record up to 3 box indices in stable order
// ---------------------------------------------------------------------------
__global__ __launch_bounds__(256) void k_bucket(const int* __restrict__ labels,
                                                int* __restrict__ boxidx) {
  __shared__ int lab[NBPER];
  const int b = blockIdx.x, tid = threadIdx.x;
  if (tid < NBPER) lab[tid] = labels[b * NBPER + tid];
  __syncthreads();
  if (tid < CC) {
    int cnt = 0;
    int out[3] = {-1, -1, -1};
    for (int i = 0; i < NBPER; ++i) {
      if (lab[i] == tid + 1 && cnt < 3) { out[cnt] = b * NBPER + i; ++cnt; }
    }
    const int base = (b * CC + tid) * 3;
    boxidx[base] = out[0]; boxidx[base + 1] = out[1]; boxidx[base + 2] = out[2];
  }
}

// ---------------------------------------------------------------------------
// KB: x[b,c,d] = lin_b + sum_slot lin_w[slot]*full[box][d], bf16, K-padded
// ---------------------------------------------------------------------------
__global__ __launch_bounds__(256) void k_buildx(const float* __restrict__ imgf,
                                                const float* __restrict__ bbox,
                                                const float* __restrict__ lw,
                                                const float* __restrict__ lb,
                                                const int* __restrict__ boxidx,
                                                unsigned short* __restrict__ xbf) {
  const int c = blockIdx.x, b = blockIdx.y;
  const int r = b * CC + c;
  const int base = r * 3;
  const int i0 = boxidx[base], i1 = boxidx[base + 1], i2 = boxidx[base + 2];
  const float w0 = lw[0], w1 = lw[1], w2 = lw[2], bias = lb[0];
  for (int s = threadIdx.x; s < KP / 8; s += 256) {
    const int d0 = s * 8;
    float v[8];
#pragma unroll
    for (int q = 0; q < 8; ++q) v[q] = 0.f;
    if (d0 < 2048) {
      if (i0 >= 0) {
        const float4* p = (const float4*)(imgf + (size_t)i0 * 2048 + d0);
        float4 u0 = p[0], u1 = p[1];
        v[0] += w0 * u0.x; v[1] += w0 * u0.y; v[2] += w0 * u0.z; v[3] += w0 * u0.w;
        v[4] += w0 * u1.x; v[5] += w0 * u1.y; v[6] += w0 * u1.z; v[7] += w0 * u1.w;
      }
      if (i1 >= 0) {
        const float4* p = (const float4*)(imgf + (size_t)i1 * 2048 + d0);
        float4 u0 = p[0], u1 = p[1];
        v[0] += w1 * u0.x; v[1] += w1 * u0.y; v[2] += w1 * u0.z; v[3] += w1 * u0.w;
        v[4] += w1 * u1.x; v[5] += w1 * u1.y; v[6] += w1 * u1.z; v[7] += w1 * u1.w;
      }
      if (i2 >= 0) {
        const float4* p = (const float4*)(imgf + (size_t)i2 * 2048 + d0);
        float4 u0 = p[0], u1 = p[1];
        v[0] += w2 * u0.x; v[1] += w2 * u0.y; v[2] += w2 * u0.z; v[3] += w2 * u0.w;
        v[4] += w2 * u1.x; v[5] += w2 * u1.y; v[6] += w2 * u1.z; v[7] += w2 * u1.w;
      }
#pragma unroll
      for (int q = 0; q < 8; ++q) v[q] += bias;
    } else if (d0 == 2048) {
      // cols 2048..2051 = bbox, 2052..2055 = pad(0)
      if (i0 >= 0) { float4 u = *(const float4*)(bbox + (size_t)i0 * 4);
        v[0] += w0 * u.x; v[1] += w0 * u.y; v[2] += w0 * u.z; v[3] += w0 * u.w; }
      if (i1 >= 0) { float4 u = *(const float4*)(bbox + (size_t)i1 * 4);
        v[0] += w1 * u.x; v[1] += w1 * u.y; v[2] += w1 * u.z; v[3] += w1 * u.w; }
      if (i2 >= 0) { float4 u = *(const float4*)(bbox + (size_t)i2 * 4);
        v[0] += w2 * u.x; v[1] += w2 * u.y; v[2] += w2 * u.z; v[3] += w2 * u.w; }
      v[0] += bias; v[1] += bias; v[2] += bias; v[3] += bias;
    } // d0 > 2048: zero padding
    unsigned short o[8] __attribute__((aligned(16)));
#pragma unroll
    for (int q = 0; q < 8; ++q) o[q] = f2bf(v[q]);
    *(uint4*)(xbf + (size_t)r * KP + d0) = *(const uint4*)o;
  }
}

// ---------------------------------------------------------------------------
// KC: support[6400][2048] bf16 = x_bf16[6400][2112] @ gcwT[2048][2112]^T
// 128x128 tile, BK=64, bf16 MFMA 16x16x32, global_load_lds width-16 staging,
// k-rotation swizzle (element (m,k) stored at m*64 + ((k + 8*(m&7)) & 63)).
// ---------------------------------------------------------------------------
__global__ __launch_bounds__(256) void k_gemm1(const unsigned short* __restrict__ A,
                                               const unsigned short* __restrict__ Bt,
                                               unsigned short* __restrict__ Cb) {
  __shared__ unsigned short Asm[128 * 64] __attribute__((aligned(16)));
  __shared__ unsigned short Bsm[128 * 64] __attribute__((aligned(16)));
  const int tid  = threadIdx.x;
  const int lane = tid & 63;
  const int w    = tid >> 6;          // wave 0..3
  const int m0   = blockIdx.y * 128;  // 50 tiles
  const int n0   = blockIdx.x * 128;  // 16 tiles
  const int wm   = (w & 1) * 64;
  const int wn   = (w >> 1) * 64;
  // staging: lane l fills LDS chunk elements [l*8, l*8+8) = row chunk*8+(l>>3), perm-slots (l&7)*8..
  const int srow = lane >> 3;                      // row within 8-row chunk (== m&7)
  const int gk   = (((lane & 7) - srow) & 7) * 8;  // global k start for this lane (swizzle inverse)
  const int quad = lane >> 4;
  const int lrow = lane & 15;
  const int rot  = (lane & 7) * 8;                 // == 8*(m&7) for fragment rows

  floatx4 acc[4][4] = {};

  for (int kb = 0; kb < KP / 64; ++kb) {
    const int k0 = kb * 64;
#pragma unroll
    for (int t = 0; t < 4; ++t) {
      const int chunk = t * 4 + w;
      const int row = chunk * 8 + srow;
      async16(A  + (size_t)(m0 + row) * KP + (k0 + gk), &Asm[chunk * 512]);
      async16(Bt + (size_t)(n0 + row) * KP + (k0 + gk), &Bsm[chunk * 512]);
    }
    __syncthreads();  // drains vmcnt (global_load_lds) + barrier
#pragma unroll
    for (int kp = 0; kp < 2; ++kp) {
      const int koff = (kp * 32 + quad * 8 + rot) & 63;
      short8 af[4], bfr[4];
#pragma unroll
      for (int i = 0; i < 4; ++i)
        af[i]  = *(const short8*)&Asm[(wm + i * 16 + lrow) * 64 + koff];
#pragma unroll
      for (int j = 0; j < 4; ++j)
        bfr[j] = *(const short8*)&Bsm[(wn + j * 16 + lrow) * 64 + koff];
#pragma unroll
      for (int i = 0; i < 4; ++i)
#pragma unroll
        for (int j = 0; j < 4; ++j)
          acc[i][j] = __builtin_amdgcn_mfma_f32_16x16x32_bf16(af[i], bfr[j], acc[i][j], 0, 0, 0);
    }
    __syncthreads();
  }
  // epilogue: C/D layout col=lane&15, row=(lane>>4)*4+reg ; store bf16
#pragma unroll
  for (int i = 0; i < 4; ++i)
#pragma unroll
    for (int j = 0; j < 4; ++j) {
      const int col = n0 + wn + j * 16 + lrow;
#pragma unroll
      for (int rr = 0; rr < 4; ++rr) {
        const int row = m0 + wm + i * 16 + quad * 4 + rr;
        Cb[(size_t)row * NOUT + col] = f2bf(acc[i][j][rr]);
      }
    }
}

// ---------------------------------------------------------------------------
// KD: out[b,o] = sum_c g[b,c] * lrelu( sum_n (X[c,n]+adj[b,c,n]) * S[b,n,o] + gc_b[o] )
// bf16 MFMA: per block (b, 128-o tile): T = A2(128c x 128k) @ S^T(128o x 128k),
// fused bias+leaky_relu+g-weight+c-reduction epilogue. k-rotation swizzled LDS.
// ---------------------------------------------------------------------------
__global__ __launch_bounds__(256) void k_gemm2(const float* __restrict__ X,
                                               const float* __restrict__ adj,
                                               const unsigned short* __restrict__ S,
                                               const float* __restrict__ gf,
                                               const float* __restrict__ gcb,
                                               float* __restrict__ outp) {
  __shared__ unsigned int A2w[128 * 64] __attribute__((aligned(16)));  // bf16x2 [c][kpair swz]
  __shared__ unsigned int Ssw[128 * 64] __attribute__((aligned(16)));  // bf16x2 [o][kpair swz]
  __shared__ float gsm[128];
  const int tid = threadIdx.x;
  const int o0  = blockIdx.x * 128;
  const int b   = blockIdx.y;

  if (tid < 128) gsm[tid] = (tid < CC) ? gf[b * CC + tid] : 0.f;

  // stage A2[c][n] = X[c][n] + adj[b][c][n] (zero-pad c>=100, n>=100), swizzled bf16 pairs
#pragma unroll
  for (int it = 0; it < 32; ++it) {
    const int idx = it * 256 + tid;
    const int c = idx >> 6, j = idx & 63;   // j = n-pair index
    unsigned int v = 0;
    if (c < CC && j < 50) {
      const float2 a2 = *(const float2*)(adj + (size_t)b * (CC * CC) + c * CC + 2 * j);
      const float2 x2 = *(const float2*)(X + c * CC + 2 * j);
      v = (unsigned int)f2bf(a2.x + x2.x) | ((unsigned int)f2bf(a2.y + x2.y) << 16);
    }
    A2w[c * 64 + ((j + 4 * (c & 15)) & 63)] = v;
  }
  // stage S^T[o][n] from bf16 S rows (transpose via LDS), swizzled bf16 pairs
#pragma unroll
  for (int it = 0; it < 32; ++it) {
    const int idx = it * 256 + tid;
    const int o = idx & 127, np = idx >> 7;  // np = n-pair index
    unsigned int v = 0;
    const int n0 = 2 * np;
    if (n0 < CC) {
      unsigned int lo = S[(size_t)(b * CC + n0) * NOUT + o0 + o];
      unsigned int hi = (n0 + 1 < CC) ? (unsigned int)S[(size_t)(b * CC + n0 + 1) * NOUT + o0 + o] : 0u;
      v = lo | (hi << 16);
    }
    Ssw[o * 64 + ((np + 4 * (o & 15)) & 63)] = v;
  }
  __syncthreads();

  const int lane = tid & 63;
  const int w    = tid >> 6;
  const int wm   = (w & 1) * 64;
  const int wn   = (w >> 1) * 64;
  const int quad = lane >> 4;
  const int lrow = lane & 15;

  floatx4 acc[4][4] = {};
#pragma unroll
  for (int kp = 0; kp < 4; ++kp) {
    const int kw = (kp * 16 + quad * 4 + 4 * lrow) & 63;  // word offset (swizzle-matched)
    short8 af[4], bfr[4];
#pragma unroll
    for (int i = 0; i < 4; ++i)
      af[i] = *(const short8*)&A2w[(wm + i * 16 + lrow) * 64 + kw];
#pragma unroll
    for (int j = 0; j < 4; ++j)
      bfr[j] = *(const short8*)&Ssw[(wn + j * 16 + lrow) * 64 + kw];
#pragma unroll
    for (int i = 0; i < 4; ++i)
#pragma unroll
      for (int j = 0; j < 4; ++j)
        acc[i][j] = __builtin_amdgcn_mfma_f32_16x16x32_bf16(af[i], bfr[j], acc[i][j], 0, 0, 0);
  }
  __syncthreads();  // all fragment reads done; A2w reusable as reduction buffer

  // epilogue: T[c][o] = acc; out_o = sum_c g[c]*lrelu(T+bias[o])
  float* red = (float*)A2w;  // [o_local][9] slots, 128*9*4B = 4.6 KB
  const int slot = (w & 1) * 4 + quad;
#pragma unroll
  for (int j = 0; j < 4; ++j) {
    const int ol = wn + j * 16 + lrow;
    const float bias = gcb[o0 + ol];
    float s = 0.f;
#pragma unroll
    for (int i = 0; i < 4; ++i) {
#pragma unroll
      for (int rr = 0; rr < 4; ++rr) {
        const int c = wm + i * 16 + quad * 4 + rr;
        float t = acc[i][j][rr] + bias;
        t = (t > 0.f) ? t : 0.01f * t;
        s += gsm[c] * t;   // gsm[c]=0 for c>=100 masks the pad rows
      }
    }
    red[ol * 9 + slot] = s;
  }
  __syncthreads();
  if (tid < 128) {
    float s = 0.f;
#pragma unroll
    for (int t = 0; t < 8; ++t) s += red[tid * 9 + t];
    outp[(size_t)b * NOUT + o0 + tid] = s;
  }
}

// ---------------------------------------------------------------------------
extern "C" void kernel_launch(void* const* d_in, const int* in_sizes, int n_in,
                              void* d_out, int out_size, void* d_ws, size_t ws_size,
                              hipStream_t stream) {
  const float* imgf   = (const float*)d_in[0];
  const float* bbox   = (const float*)d_in[1];
  const float* gfeat  = (const float*)d_in[2];
  const float* adj    = (const float*)d_in[3];
  const float* X      = (const float*)d_in[4];
  const float* lw     = (const float*)d_in[5];
  const float* lb     = (const float*)d_in[6];
  const float* gcw    = (const float*)d_in[7];
  const float* gcb    = (const float*)d_in[8];
  const int*   labels = (const int*)d_in[9];

  char* ws = (char*)d_ws;
  // ws layout (16B-aligned): total ~62 MB
  int*            boxidx   = (int*)(ws);                         //    76,800 B
  unsigned short* xbf      = (unsigned short*)(ws + 76800);      // 27,033,600 B
  unsigned short* gcwT     = (unsigned short*)(ws + 27110400);   //  8,650,752 B
  unsigned short* supportB = (unsigned short*)(ws + 35761152);   // 26,214,400 B
  float*          outp     = (float*)d_out;

  k_transpose<<<dim3(KP / 32, NOUT / 32), dim3(32, 8), 0, stream>>>(gcw, gcwT);
  k_bucket<<<dim3(BB), dim3(256), 0, stream>>>(labels, boxidx);
  k_buildx<<<dim3(CC, BB), dim3(256), 0, stream>>>(imgf, bbox, lw, lb, boxidx, xbf);
  k_gemm1<<<dim3(NOUT / 128, MR / 128), dim3(256), 0, stream>>>(xbf, gcwT, supportB);
  k_gemm2<<<dim3(NOUT / 128, BB), dim3(256), 0, stream>>>(X, adj, supportB, gfeat, gcb, outp);
}